// Round 16
// baseline (402.072 us; speedup 1.0000x reference)
//
#include <hip/hip_runtime.h>

#define DI __device__ __forceinline__

constexpr int BATCH = 256;
constexpr int INF   = 4096;   // in_features
constexpr int NGRP  = 1024;   // INF/4
constexpr int MOUT  = 4096;   // out_features

using bf16x8 = __attribute__((ext_vector_type(8))) short;
using f32x4  = __attribute__((ext_vector_type(4))) float;

// D4 half-codebook, stored as 2x the actual values (int8); actual = v * 0.5
__device__ __constant__ signed char D4_I8[512] = {
     0, 0, 0, 0,  -4, 0, 0, 0,  -2,-2,-2,-2,  -2,-2,-2, 0,  -2,-2,-2, 2,  -2,-2, 0,-2,  -2,-2, 0, 0,  -2,-2, 0, 2,
    -2,-2, 2,-2,  -2,-2, 2, 0,  -2,-2, 2, 2,  -2, 0,-2,-2,  -2, 0,-2, 0,  -2, 0,-2, 2,  -2, 0, 0,-2,  -2, 0, 0, 0,
    -2, 0, 0, 2,  -2, 0, 2,-2,  -2, 0, 2, 0,  -2, 0, 2, 2,  -2, 2,-2,-2,  -2, 2,-2, 0,  -2, 2,-2, 2,  -2, 2, 0,-2,
    -2, 2, 0, 0,  -2, 2, 0, 2,  -2, 2, 2,-2,  -2, 2, 2, 0,  -2, 2, 2, 2,   0,-4, 0, 0,   0,-2,-2,-2,   0,-2,-2, 0,
     0,-2,-2, 2,   0,-2, 0,-2,   0,-2, 0, 0,   0,-2, 0, 2,   0,-2, 2,-2,   0,-2, 2, 0,   0,-2, 2, 2,   0, 0,-4, 0,
     0, 0,-2,-2,   0, 0,-2, 0,   0, 0,-2, 2,   0, 0, 0,-4,   0, 0, 0,-2,
    -3,-1,-3,-1,  -3,-1,-3, 1,  -3,-1,-1,-3,  -3,-1,-1,-1,  -3,-1,-1, 1,  -3,-1,-1, 3,  -3,-1, 1,-3,  -3,-1, 1,-1,
    -3,-1, 1, 1,  -3,-1, 1, 3,  -3,-1, 3,-1,  -3,-1, 3, 1,  -3, 1,-3,-1,  -3, 1,-3, 1,  -3, 1,-1,-3,  -3, 1,-1,-1,
    -3, 1,-1, 1,  -3, 1,-1, 3,  -3, 1, 1,-3,  -3, 1, 1,-1,  -3, 1, 1, 1,  -3, 1, 1, 3,  -3, 1, 3,-1,  -3, 1, 3, 1,
    -3, 3,-1,-1,  -3, 3, 1,-1,  -3, 3, 1, 1,  -1,-3,-3,-1,  -1,-3,-3, 1,  -1,-3,-1,-3,  -1,-3,-1,-1,  -1,-3,-1, 1,
    -1,-3,-1, 3,  -1,-3, 1,-3,  -1,-3, 1,-1,  -1,-3, 1, 1,  -1,-3, 1, 3,  -1,-3, 3,-1,  -1,-3, 3, 1,  -1,-1,-3,-3,
    -1,-1,-3,-1,  -1,-1,-3, 1,  -1,-1,-3, 3,  -1,-1,-1,-3,  -1,-1,-1,-1,  -1,-1,-1, 1,  -1,-1,-1, 3,  -1,-1, 1,-3,
    -1,-1, 1,-1,  -1,-1, 1, 1,  -1,-1, 1, 3,  -1,-1, 3,-3,  -1,-1, 3,-1,  -1,-1, 3, 1,  -1,-1, 3, 3,  -1, 1,-3,-3,
    -1, 1,-3,-1,  -1, 1,-3, 1,  -1, 1,-3, 3,  -1, 1,-1,-3,  -1, 1,-1,-1,  -1, 1,-1, 1,  -1, 1,-1, 3,  -1, 1, 1,-3,
    -1, 1, 1,-1,  -1, 1, 1, 1,  -1, 1, 1, 3,  -1, 1, 3,-3,  -1, 1, 3,-1,  -1, 1, 3, 1,  -1, 1, 3, 3,  -1, 3,-3,-1,
    -1, 3,-3, 1,  -1, 3,-1,-3,  -1, 3,-1,-1,  -1, 3,-1, 1,  -1, 3,-1, 3,  -1, 3, 1,-3,  -1, 3, 1,-1,  -1, 3, 1, 1,
    -1, 3, 1, 3,  -1, 3, 3,-1,  -1, 3, 3, 1
};

DI unsigned short f2bf(float f) {  // f32 -> bf16 bits, round-to-nearest-even
  unsigned int u = __float_as_uint(f);
  u += 0x7fffu + ((u >> 16) & 1u);
  return (unsigned short)(u >> 16);
}

// Fused prep + repack (one dispatch).
__global__ __launch_bounds__(256) void prep_kernel(
    const float* __restrict__ inp, const float* __restrict__ sw,
    const float* __restrict__ qs, const int* __restrict__ qidx,
    unsigned short* __restrict__ xa, unsigned short* __restrict__ qp) {
  __shared__ unsigned short lw[16384];     // 32 KB (repack blocks only)
  const int t = threadIdx.x;

  if (blockIdx.x < 512) {                  // ---- prep part
    int i  = blockIdx.x * 256 + t;         // 16B slot id, 131072 total
    int j  = i & 3;
    int m  = (i >> 2) & 255;
    int kb = i >> 10;
    const float* ip = inp + (size_t)m * INF + kb * 32 + j * 8;
    float4 f0 = *reinterpret_cast<const float4*>(ip);
    float4 f1 = *reinterpret_cast<const float4*>(ip + 4);
    const float* sp = sw + kb * 32 + j * 8;
    float4 s0 = *reinterpret_cast<const float4*>(sp);
    float4 s1 = *reinterpret_cast<const float4*>(sp + 4);
    int g = kb * 8 + j * 2;
    float q0 = qs[g], q1 = qs[g + 1];
    union { unsigned short u[8]; uint4 v; } o;
    o.u[0] = f2bf(f0.x * s0.x * q0); o.u[1] = f2bf(f0.y * s0.y * q0);
    o.u[2] = f2bf(f0.z * s0.z * q0); o.u[3] = f2bf(f0.w * s0.w * q0);
    o.u[4] = f2bf(f1.x * s1.x * q1); o.u[5] = f2bf(f1.y * s1.y * q1);
    o.u[6] = f2bf(f1.z * s1.z * q1); o.u[7] = f2bf(f1.w * s1.w * q1);
    reinterpret_cast<uint4*>(xa)[i] = o.v;
    return;
  }

  // ---- repack part (r6 kernel, verified)
  const int n0 = (blockIdx.x - 512) * 32;
  char* lwb = reinterpret_cast<char*>(lw);
  const int b4w   = t >> 1;
  const int cbase = b4w * 256 + ((2 * t) & 3) * 2;
  const int xk    = (b4w & 31) << 3;
  for (int r = 0; r < 32; ++r) {
    int4 v = *reinterpret_cast<const int4*>(
        qidx + (size_t)(n0 + r) * NGRP + t * 4);
    unsigned p01 = (v.x & 255) | ((v.y & 255) << 8) |
                   ((v.z & 255) << 16) | ((unsigned)(v.w & 255) << 24);
    *reinterpret_cast<unsigned*>(lwb + cbase + ((r * 8) ^ xk)) = p01;
  }
  __syncthreads();
  for (int it = 0; it < 16; ++it) {
    int b4 = it * 8 + (t >> 5);
    int n  = t & 31;
    unsigned long long v = *reinterpret_cast<const unsigned long long*>(
        lwb + b4 * 256 + ((n * 8) ^ ((b4 & 31) << 3)));
    *reinterpret_cast<unsigned long long*>(
        reinterpret_cast<char*>(qp) + (size_t)b4 * 32768 +
        (size_t)(n0 + n) * 8) = v;
  }
}

#define MM(A, B, C) C = __builtin_amdgcn_mfma_f32_16x16x32_bf16(A, B, C, 0, 0, 0)
#define LD8(p) (*reinterpret_cast<const bf16x8*>(p))

#define BAR() do { \
    asm volatile("s_waitcnt lgkmcnt(0)\n\ts_barrier" ::: "memory"); \
    __builtin_amdgcn_sched_barrier(0); } while (0)

#define STG(QV, BUF) do { \
    ulonglong2 w_; \
    w_.x = tbl[(QV) & 255]; w_.y = tbl[(QV) >> 8]; \
    *reinterpret_cast<ulonglong2*>(wsm + wbase + (BUF) + wslot) = w_; } while (0)

#define AL(AB, T) do { \
    AB##_0 = LD8(axb + (size_t)(T) * 32768 +     0); \
    AB##_1 = LD8(axb + (size_t)(T) * 32768 +  1024); \
    AB##_2 = LD8(axb + (size_t)(T) * 32768 + 16384); \
    AB##_3 = LD8(axb + (size_t)(T) * 32768 + 17408); } while (0)

// Common preamble shared by gemm and probes (same mappings, same regs).
#define GEMM_PREAMBLE(BLKID)                                                 \
  const int tid  = threadIdx.x;                                              \
  const int lane = tid & 63;                                                 \
  const int wave = tid >> 6;                                                 \
  const int mh   = wave >> 2;                                                \
  const int kq   = wave & 3;                                                 \
  const int l15  = lane & 15, l4 = lane >> 4;                                \
  const int bid = (BLKID);                                                   \
  const int ns  = bid & 127;                                                 \
  const int mt  = bid >> 7;                                                  \
  const int n0  = ns * 32;                                                   \
  const int m0  = mt * 128 + mh * 32;                                        \
  const int kqs = tid >> 8;                                                  \
  const int qn  = (tid & 255) >> 3;                                          \
  const int j2  = tid & 7;                                                   \
  const unsigned wbase = (unsigned)(kqs * 8192);                             \
  const unsigned wslot =                                                     \
      ((unsigned)(qn * 128 + j2 * 16)) ^ ((unsigned)(qn & 7) << 4);          \
  const char* qpb = reinterpret_cast<const char*>(qp) +                      \
      (size_t)(kqs * 32 + (j2 >> 2)) * 32768 + (size_t)(n0 + qn) * 8 +       \
      (j2 & 3) * 2;                                                          \
  const char* axb = reinterpret_cast<const char*>(xa) +                      \
      (size_t)(kq * 32) * 16384 + (size_t)(m0 + l15) * 64 + l4 * 16;         \
  const unsigned swzB = (unsigned)(l15 & 7) << 4;                            \
  const unsigned kqW  = (unsigned)(kq * 8192);                               \
  const unsigned rb00 = ((unsigned)(l15 * 128 + l4 * 16)) ^ swzB;            \
  const unsigned rb10 = ((unsigned)(l15 * 128 + 64 + l4 * 16)) ^ swzB;

#define QPRELOAD()                                                           \
  const unsigned Qs0 = QLD(0),  Qs1 = QLD(1),  Qs2 = QLD(2),  Qs3 = QLD(3);  \
  const unsigned Qs4 = QLD(4),  Qs5 = QLD(5),  Qs6 = QLD(6),  Qs7 = QLD(7);  \
  const unsigned Qs8 = QLD(8),  Qs9 = QLD(9),  Qsa = QLD(10), Qsb = QLD(11); \
  const unsigned Qsc = QLD(12), Qsd = QLD(13), Qse = QLD(14), Qsf = QLD(15);
#define QLD(K) ((unsigned)*reinterpret_cast<const unsigned short*>(qpb + (size_t)(K) * 65536))

#define TBLBUILD()                                                           \
  if (tid < 256) {                                                           \
    int r = tid & 127, sg = tid >> 7;                                        \
    unsigned long long v = 0;                                                \
    _Pragma("unroll")                                                        \
    for (int j = 0; j < 4; ++j) {                                            \
      float f = (float)D4_I8[r * 4 + j] * 0.5f;                              \
      unsigned int b = __float_as_uint(f) ^ (sg ? 0x80000000u : 0u);         \
      v |= (unsigned long long)(b >> 16) << (16 * j);                        \
    }                                                                        \
    tbl[tid] = v;                                                            \
  }

// ---------------- production gemm (r15, byte-identical behavior) -----------
#define STEPA(T, QN) do { \
    const char* wp_ = wsm + kqW + ((T) & 1) * 4096; \
    bf16x8 b00 = LD8(wp_ + rb00); \
    bf16x8 b01 = LD8(wp_ + rb00 + 2048); \
    bf16x8 b10 = LD8(wp_ + rb10); \
    bf16x8 b11 = LD8(wp_ + rb10 + 2048); \
    STG(QN, (((T) + 1) & 1) * 4096); \
    AL(AO, (T) + 1); \
    MM(AE_0, b00, c00); MM(AE_0, b01, c01); \
    MM(AE_1, b00, c10); MM(AE_1, b01, c11); \
    MM(AE_2, b10, c00); MM(AE_2, b11, c01); \
    MM(AE_3, b10, c10); MM(AE_3, b11, c11); \
    BAR(); } while (0)
#define STEPB(T, QN) do { \
    const char* wp_ = wsm + kqW + ((T) & 1) * 4096; \
    bf16x8 b00 = LD8(wp_ + rb00); \
    bf16x8 b01 = LD8(wp_ + rb00 + 2048); \
    bf16x8 b10 = LD8(wp_ + rb10); \
    bf16x8 b11 = LD8(wp_ + rb10 + 2048); \
    STG(QN, (((T) + 1) & 1) * 4096); \
    AL(AE, (T) + 1); \
    MM(AO_0, b00, c00); MM(AO_0, b01, c01); \
    MM(AO_1, b00, c10); MM(AO_1, b01, c11); \
    MM(AO_2, b10, c00); MM(AO_2, b11, c01); \
    MM(AO_3, b10, c10); MM(AO_3, b11, c11); \
    BAR(); } while (0)

__global__ __launch_bounds__(1024, 4) void gemm_kernel(
    const unsigned short* __restrict__ xa, const unsigned short* __restrict__ qp,
    float* __restrict__ out) {
  __shared__ unsigned long long tbl[256];
  __shared__ float red[12][1152];
  char* wsm = reinterpret_cast<char*>(red);

  GEMM_PREAMBLE(blockIdx.x)
  QPRELOAD()

  bf16x8 AE_0, AE_1, AE_2, AE_3, AO_0, AO_1, AO_2, AO_3;
  f32x4  c00 = {}, c01 = {}, c10 = {}, c11 = {};

  AL(AE, 0);
  TBLBUILD()
  BAR();
  STG(Qs0, 0);
  BAR();

  STEPA(0,  Qs1); STEPB(1,  Qs2); STEPA(2,  Qs3); STEPB(3,  Qs4);
  STEPA(4,  Qs5); STEPB(5,  Qs6); STEPA(6,  Qs7); STEPB(7,  Qs8);
  STEPA(8,  Qs9); STEPB(9,  Qsa); STEPA(10, Qsb); STEPB(11, Qsc);
  STEPA(12, Qsd); STEPB(13, Qse); STEPA(14, Qsf);
  {
    const char* wp_ = wsm + kqW + 4096;
    bf16x8 b00 = LD8(wp_ + rb00);
    bf16x8 b01 = LD8(wp_ + rb00 + 2048);
    bf16x8 b10 = LD8(wp_ + rb10);
    bf16x8 b11 = LD8(wp_ + rb10 + 2048);
    MM(AO_0, b00, c00); MM(AO_0, b01, c01);
    MM(AO_1, b00, c10); MM(AO_1, b01, c11);
    MM(AO_2, b10, c00); MM(AO_2, b11, c01);
    MM(AO_3, b10, c10); MM(AO_3, b11, c11);
  }
  BAR();

#define PWR(C, MI, NI) do { \
    pl[((MI) * 16 + l4 * 4 + 0) * 36 + (NI) * 16 + l15] = C[0]; \
    pl[((MI) * 16 + l4 * 4 + 1) * 36 + (NI) * 16 + l15] = C[1]; \
    pl[((MI) * 16 + l4 * 4 + 2) * 36 + (NI) * 16 + l15] = C[2]; \
    pl[((MI) * 16 + l4 * 4 + 3) * 36 + (NI) * 16 + l15] = C[3]; } while (0)
#define PRD(C, MI, NI) do { \
    C[0] += pl[((MI) * 16 + l4 * 4 + 0) * 36 + (NI) * 16 + l15]; \
    C[1] += pl[((MI) * 16 + l4 * 4 + 1) * 36 + (NI) * 16 + l15]; \
    C[2] += pl[((MI) * 16 + l4 * 4 + 2) * 36 + (NI) * 16 + l15]; \
    C[3] += pl[((MI) * 16 + l4 * 4 + 3) * 36 + (NI) * 16 + l15]; } while (0)

  if (kq) {
    float* pl = &red[mh * 3 + kq - 1][0];
    PWR(c00, 0, 0); PWR(c01, 0, 1); PWR(c10, 1, 0); PWR(c11, 1, 1);
  }
  __syncthreads();
  if (kq == 0) {
#pragma unroll
    for (int p = 0; p < 3; ++p) {
      const float* pl = &red[mh * 3 + p][0];
      PRD(c00, 0, 0); PRD(c01, 0, 1); PRD(c10, 1, 0); PRD(c11, 1, 1);
    }
    float* ob = out + (size_t)(m0 + l4 * 4) * MOUT + n0 + l15;
#define STO(C, MI, NI) do { \
    ob[(size_t)((MI) * 16 + 0) * MOUT + (NI) * 16] = C[0]; \
    ob[(size_t)((MI) * 16 + 1) * MOUT + (NI) * 16] = C[1]; \
    ob[(size_t)((MI) * 16 + 2) * MOUT + (NI) * 16] = C[2]; \
    ob[(size_t)((MI) * 16 + 3) * MOUT + (NI) * 16] = C[3]; } while (0)
    STO(c00, 0, 0); STO(c01, 0, 1); STO(c10, 1, 0); STO(c11, 1, 1);
#undef STO
  }
#undef PWR
#undef PRD
}

// ---------------- diagnostic probes: gemm hot loop x4, component-ablated ---
// V0 full | V1 no-staging | V2 no-B-reads | V3 no-A-loads. Identical
// geometry/LDS/barriers to gemm_kernel; keep-alives prevent DCE (rule #17).
#define PSTEP(T, QN, ABc, ABn) do { \
    bf16x8 b00, b01, b10, b11; \
    if constexpr (V != 2) { \
      const char* wp_ = wsm + kqW + ((T) & 1) * 4096; \
      b00 = LD8(wp_ + rb00); b01 = LD8(wp_ + rb00 + 2048); \
      b10 = LD8(wp_ + rb10); b11 = LD8(wp_ + rb10 + 2048); \
    } else { b00 = ABc##_0; b01 = ABc##_1; b10 = ABc##_2; b11 = ABc##_3; } \
    if constexpr (V != 1) STG(QN, (((T) + 1) & 1) * 4096); \
    if constexpr (V != 3) AL(ABn, (T) + 1); \
    MM(ABc##_0, b00, c00); MM(ABc##_0, b01, c01); \
    MM(ABc##_1, b00, c10); MM(ABc##_1, b01, c11); \
    MM(ABc##_2, b10, c00); MM(ABc##_2, b11, c01); \
    MM(ABc##_3, b10, c10); MM(ABc##_3, b11, c11); \
    BAR(); } while (0)

template <int V>
__global__ __launch_bounds__(1024, 4) void probe_kernel(
    const unsigned short* __restrict__ xa, const unsigned short* __restrict__ qp,
    float* __restrict__ dst) {
  __shared__ unsigned long long tbl[256];
  __shared__ float red[12][1152];
  char* wsm = reinterpret_cast<char*>(red);

  GEMM_PREAMBLE(blockIdx.x)
  QPRELOAD()

  bf16x8 AE_0, AE_1, AE_2, AE_3, AO_0, AO_1, AO_2, AO_3;
  f32x4  c00 = {}, c01 = {}, c10 = {}, c11 = {};

  AL(AE, 0);
  AO_0 = AE_0; AO_1 = AE_1; AO_2 = AE_2; AO_3 = AE_3;
  TBLBUILD()
  BAR();
  STG(Qs0, 0);
  BAR();

#pragma unroll 1
  for (int rep = 0; rep < 4; ++rep) {
    PSTEP(0,  Qs1, AE, AO); PSTEP(1,  Qs2, AO, AE);
    PSTEP(2,  Qs3, AE, AO); PSTEP(3,  Qs4, AO, AE);
    PSTEP(4,  Qs5, AE, AO); PSTEP(5,  Qs6, AO, AE);
    PSTEP(6,  Qs7, AE, AO); PSTEP(7,  Qs8, AO, AE);
    PSTEP(8,  Qs9, AE, AO); PSTEP(9,  Qsa, AO, AE);
    PSTEP(10, Qsb, AE, AO); PSTEP(11, Qsc, AO, AE);
    PSTEP(12, Qsd, AE, AO); PSTEP(13, Qse, AO, AE);
    PSTEP(14, Qsf, AE, AO); PSTEP(15, Qs0, AO, AE);   // wraps buf parity
  }

  float sum = 0.f;
#pragma unroll
  for (int r = 0; r < 4; ++r)
    sum += c00[r] + c01[r] + c10[r] + c11[r];
  sum += (float)(Qs0 + Qs1 + Qs2 + Qs3 + Qs4 + Qs5 + Qs6 + Qs7 +
                 Qs8 + Qs9 + Qsa + Qsb + Qsc + Qsd + Qse + Qsf) * 1e-30f;
  dst[(size_t)bid * 1024 + tid] = sum;
}

extern "C" void kernel_launch(void* const* d_in, const int* in_sizes, int n_in,
                              void* d_out, int out_size, void* d_ws, size_t ws_size,
                              hipStream_t stream) {
  const float* inp = (const float*)d_in[0];
  const float* sw  = (const float*)d_in[1];
  const float* qs  = (const float*)d_in[2];
  const int*   qi  = (const int*)d_in[3];
  float* out = (float*)d_out;
  unsigned short* xa = (unsigned short*)d_ws;                       // 2 MB
  unsigned short* qp = (unsigned short*)((char*)d_ws + (4 << 20));  // 4 MB
  float* pd = (float*)((char*)d_ws + (8 << 20));                    // 4 x 1 MB

  prep_kernel<<<640, 256, 0, stream>>>(inp, sw, qs, qi, xa, qp);

  // ---- diagnostics (scratch output; per-dispatch counters via rocprof)
  probe_kernel<0><<<256, 1024, 0, stream>>>(xa, qp, pd);
  probe_kernel<1><<<256, 1024, 0, stream>>>(xa, qp, pd + (1 << 18));
  probe_kernel<2><<<256, 1024, 0, stream>>>(xa, qp, pd + (2 << 18));
  probe_kernel<3><<<256, 1024, 0, stream>>>(xa, qp, pd + (3 << 18));

  // ---- production path (r15, unchanged)
  gemm_kernel<<<256, 1024, 0, stream>>>(xa, qp, out);
}

// Round 17
// 29.484 us; speedup vs baseline: 13.6370x; 13.6370x over previous
//
#include <hip/hip_runtime.h>

#define DI __device__ __forceinline__

constexpr int BATCH = 256;
constexpr int INF   = 4096;   // in_features
constexpr int NGRP  = 1024;   // INF/4
constexpr int MOUT  = 4096;   // out_features

using bf16x8 = __attribute__((ext_vector_type(8))) short;
using f32x4  = __attribute__((ext_vector_type(4))) float;

// D4 half-codebook, stored as 2x the actual values (int8); actual = v * 0.5
__device__ __constant__ signed char D4_I8[512] = {
     0, 0, 0, 0,  -4, 0, 0, 0,  -2,-2,-2,-2,  -2,-2,-2, 0,  -2,-2,-2, 2,  -2,-2, 0,-2,  -2,-2, 0, 0,  -2,-2, 0, 2,
    -2,-2, 2,-2,  -2,-2, 2, 0,  -2,-2, 2, 2,  -2, 0,-2,-2,  -2, 0,-2, 0,  -2, 0,-2, 2,  -2, 0, 0,-2,  -2, 0, 0, 0,
    -2, 0, 0, 2,  -2, 0, 2,-2,  -2, 0, 2, 0,  -2, 0, 2, 2,  -2, 2,-2,-2,  -2, 2,-2, 0,  -2, 2,-2, 2,  -2, 2, 0,-2,
    -2, 2, 0, 0,  -2, 2, 0, 2,  -2, 2, 2,-2,  -2, 2, 2, 0,  -2, 2, 2, 2,   0,-4, 0, 0,   0,-2,-2,-2,   0,-2,-2, 0,
     0,-2,-2, 2,   0,-2, 0,-2,   0,-2, 0, 0,   0,-2, 0, 2,   0,-2, 2,-2,   0,-2, 2, 0,   0,-2, 2, 2,   0, 0,-4, 0,
     0, 0,-2,-2,   0, 0,-2, 0,   0, 0,-2, 2,   0, 0, 0,-4,   0, 0, 0,-2,
    -3,-1,-3,-1,  -3,-1,-3, 1,  -3,-1,-1,-3,  -3,-1,-1,-1,  -3,-1,-1, 1,  -3,-1,-1, 3,  -3,-1, 1,-3,  -3,-1, 1,-1,
    -3,-1, 1, 1,  -3,-1, 1, 3,  -3,-1, 3,-1,  -3,-1, 3, 1,  -3, 1,-3,-1,  -3, 1,-3, 1,  -3, 1,-1,-3,  -3, 1,-1,-1,
    -3, 1,-1, 1,  -3, 1,-1, 3,  -3, 1, 1,-3,  -3, 1, 1,-1,  -3, 1, 1, 1,  -3, 1, 1, 3,  -3, 1, 3,-1,  -3, 1, 3, 1,
    -3, 3,-1,-1,  -3, 3, 1,-1,  -3, 3, 1, 1,  -1,-3,-3,-1,  -1,-3,-3, 1,  -1,-3,-1,-3,  -1,-3,-1,-1,  -1,-3,-1, 1,
    -1,-3,-1, 3,  -1,-3, 1,-3,  -1,-3, 1,-1,  -1,-3, 1, 1,  -1,-3, 1, 3,  -1,-3, 3,-1,  -1,-3, 3, 1,  -1,-1,-3,-3,
    -1,-1,-3,-1,  -1,-1,-3, 1,  -1,-1,-3, 3,  -1,-1,-1,-3,  -1,-1,-1,-1,  -1,-1,-1, 1,  -1,-1,-1, 3,  -1,-1, 1,-3,
    -1,-1, 1,-1,  -1,-1, 1, 1,  -1,-1, 1, 3,  -1,-1, 3,-3,  -1,-1, 3,-1,  -1,-1, 3, 1,  -1,-1, 3, 3,  -1, 1,-3,-3,
    -1, 1,-3,-1,  -1, 1,-3, 1,  -1, 1,-3, 3,  -1, 1,-1,-3,  -1, 1,-1,-1,  -1, 1,-1, 1,  -1, 1,-1, 3,  -1, 1, 1,-3,
    -1, 1, 1,-1,  -1, 1, 1, 1,  -1, 1, 1, 3,  -1, 1, 3,-3,  -1, 1, 3,-1,  -1, 1, 3, 1,  -1, 1, 3, 3,  -1, 3,-3,-1,
    -1, 3,-3, 1,  -1, 3,-1,-3,  -1, 3,-1,-1,  -1, 3,-1, 1,  -1, 3,-1, 3,  -1, 3, 1,-3,  -1, 3, 1,-1,  -1, 3, 1, 1,
    -1, 3, 1, 3,  -1, 3, 3,-1,  -1, 3, 3, 1
};

DI unsigned short f2bf(float f) {  // f32 -> bf16 bits, round-to-nearest-even
  unsigned int u = __float_as_uint(f);
  u += 0x7fffu + ((u >> 16) & 1u);
  return (unsigned short)(u >> 16);
}

// Fused prep + repack (one dispatch).
// Blocks 0..511: Xa = scaled input, fragment-linear Xa[k>>5][m][(k>>3)&3][8].
// Blocks 512..639: Qidxs -> Qp u16 [B4=k>>5][n][j=(k>>3)&3] via LDS transpose.
__global__ __launch_bounds__(256) void prep_kernel(
    const float* __restrict__ inp, const float* __restrict__ sw,
    const float* __restrict__ qs, const int* __restrict__ qidx,
    unsigned short* __restrict__ xa, unsigned short* __restrict__ qp) {
  __shared__ unsigned short lw[16384];     // 32 KB (repack blocks only)
  const int t = threadIdx.x;

  if (blockIdx.x < 512) {                  // ---- prep part
    int i  = blockIdx.x * 256 + t;         // 16B slot id, 131072 total
    int j  = i & 3;
    int m  = (i >> 2) & 255;
    int kb = i >> 10;
    const float* ip = inp + (size_t)m * INF + kb * 32 + j * 8;
    float4 f0 = *reinterpret_cast<const float4*>(ip);
    float4 f1 = *reinterpret_cast<const float4*>(ip + 4);
    const float* sp = sw + kb * 32 + j * 8;
    float4 s0 = *reinterpret_cast<const float4*>(sp);
    float4 s1 = *reinterpret_cast<const float4*>(sp + 4);
    int g = kb * 8 + j * 2;
    float q0 = qs[g], q1 = qs[g + 1];
    union { unsigned short u[8]; uint4 v; } o;
    o.u[0] = f2bf(f0.x * s0.x * q0); o.u[1] = f2bf(f0.y * s0.y * q0);
    o.u[2] = f2bf(f0.z * s0.z * q0); o.u[3] = f2bf(f0.w * s0.w * q0);
    o.u[4] = f2bf(f1.x * s1.x * q1); o.u[5] = f2bf(f1.y * s1.y * q1);
    o.u[6] = f2bf(f1.z * s1.z * q1); o.u[7] = f2bf(f1.w * s1.w * q1);
    reinterpret_cast<uint4*>(xa)[i] = o.v;
    return;
  }

  // ---- repack part (r6 kernel, verified)
  const int n0 = (blockIdx.x - 512) * 32;
  char* lwb = reinterpret_cast<char*>(lw);
  const int b4w   = t >> 1;
  const int cbase = b4w * 256 + ((2 * t) & 3) * 2;
  const int xk    = (b4w & 31) << 3;
  for (int r = 0; r < 32; ++r) {
    int4 v = *reinterpret_cast<const int4*>(
        qidx + (size_t)(n0 + r) * NGRP + t * 4);
    unsigned p01 = (v.x & 255) | ((v.y & 255) << 8) |
                   ((v.z & 255) << 16) | ((unsigned)(v.w & 255) << 24);
    *reinterpret_cast<unsigned*>(lwb + cbase + ((r * 8) ^ xk)) = p01;
  }
  __syncthreads();
  for (int it = 0; it < 16; ++it) {
    int b4 = it * 8 + (t >> 5);
    int n  = t & 31;
    unsigned long long v = *reinterpret_cast<const unsigned long long*>(
        lwb + b4 * 256 + ((n * 8) ^ ((b4 & 31) << 3)));
    *reinterpret_cast<unsigned long long*>(
        reinterpret_cast<char*>(qp) + (size_t)b4 * 32768 +
        (size_t)(n0 + n) * 8) = v;
  }
}

// ---------------- staged-W fused dequant-GEMM (r15 + BK=128) ---------------
// Grid 256 = 2 mt x 128 ns. Block 1024 thr / 16 waves = 4 mh x 4 kq; block
// tile 128m x 32n, full K in-block (kq = 1024k each). BK=128 -> only EIGHT
// in-loop barriers (r16 probes showed the kernel is per-step-overhead bound:
// ~3400+ cyc/step vs ~1000 cyc of pipe work; conflicts ~1us; no single data
// path dominant). W step-tile per kq = [32n][128k] (8 KB), XOR-swizzled rows
// (XOR applied to the fully-assembled offset; kk folded inside). lgkmcnt-only
// barriers; q for all 8 steps (2 u16/thread/step) preloaded into 16 regs.

#define MM(A, B, C) C = __builtin_amdgcn_mfma_f32_16x16x32_bf16(A, B, C, 0, 0, 0)
#define LD8(p) (*reinterpret_cast<const bf16x8*>(p))

#define BAR() do { \
    asm volatile("s_waitcnt lgkmcnt(0)\n\ts_barrier" ::: "memory"); \
    __builtin_amdgcn_sched_barrier(0); } while (0)

#define STG2(QLO, QHI, BUF) do { \
    ulonglong2 w_; \
    w_.x = tbl[(QLO) & 255]; w_.y = tbl[(QLO) >> 8]; \
    *reinterpret_cast<ulonglong2*>(wsm + wbase + (BUF) + wslot) = w_; \
    w_.x = tbl[(QHI) & 255]; w_.y = tbl[(QHI) >> 8]; \
    *reinterpret_cast<ulonglong2*>(wsm + wbase + (BUF) + wslot + 128) = w_; } while (0)

#define AL(AB, T) do { \
    const char* ax_ = axb + (size_t)(T) * 65536; \
    AB##_0 = LD8(ax_ +     0); AB##_1 = LD8(ax_ +  1024); \
    AB##_2 = LD8(ax_ + 16384); AB##_3 = LD8(ax_ + 17408); \
    AB##_4 = LD8(ax_ + 32768); AB##_5 = LD8(ax_ + 33792); \
    AB##_6 = LD8(ax_ + 49152); AB##_7 = LD8(ax_ + 50176); } while (0)

#define MFMA16(AB, b00,b01,b10,b11,b20,b21,b30,b31) do { \
    MM(AB##_0, b00, c00); MM(AB##_0, b01, c01); \
    MM(AB##_1, b00, c10); MM(AB##_1, b01, c11); \
    MM(AB##_2, b10, c00); MM(AB##_2, b11, c01); \
    MM(AB##_3, b10, c10); MM(AB##_3, b11, c11); \
    MM(AB##_4, b20, c00); MM(AB##_4, b21, c01); \
    MM(AB##_5, b20, c10); MM(AB##_5, b21, c11); \
    MM(AB##_6, b30, c00); MM(AB##_6, b31, c01); \
    MM(AB##_7, b30, c10); MM(AB##_7, b31, c11); } while (0)

#define BREADS() \
    bf16x8 b00 = LD8(wp_ + rk0), b01 = LD8(wp_ + rk0 + 4096); \
    bf16x8 b10 = LD8(wp_ + rk1), b11 = LD8(wp_ + rk1 + 4096); \
    bf16x8 b20 = LD8(wp_ + rk2), b21 = LD8(wp_ + rk2 + 4096); \
    bf16x8 b30 = LD8(wp_ + rk3), b31 = LD8(wp_ + rk3 + 4096);

#define STEPA(T, QLO, QHI) do { \
    const char* wp_ = wsm + kqW + ((T) & 1) * 8192; \
    BREADS() \
    STG2(QLO, QHI, (((T) + 1) & 1) * 8192); \
    AL(AO, (T) + 1); \
    MFMA16(AE, b00,b01,b10,b11,b20,b21,b30,b31); \
    BAR(); } while (0)
#define STEPB(T, QLO, QHI) do { \
    const char* wp_ = wsm + kqW + ((T) & 1) * 8192; \
    BREADS() \
    STG2(QLO, QHI, (((T) + 1) & 1) * 8192); \
    AL(AE, (T) + 1); \
    MFMA16(AO, b00,b01,b10,b11,b20,b21,b30,b31); \
    BAR(); } while (0)

__global__ __launch_bounds__(1024, 4) void gemm_kernel(
    const unsigned short* __restrict__ xa, const unsigned short* __restrict__ qp,
    float* __restrict__ out) {
  __shared__ unsigned long long tbl[256];   // 2 KB sign-folded bf16x4 codebook
  __shared__ ulonglong2 wt[4096];           // 64 KB: [kq(4)][buf(2)][8 KB]
  char*  wsm  = reinterpret_cast<char*>(wt);
  float* redp = reinterpret_cast<float*>(wt);   // epilogue planes alias W

  const int tid  = threadIdx.x;             // 0..1023
  const int lane = tid & 63;
  const int wave = tid >> 6;                // 0..15
  const int mh   = wave >> 2;               // m sub-tile (32 rows)
  const int kq   = wave & 3;                // k quarter (1024 k)
  const int l15  = lane & 15, l4 = lane >> 4;

  const int bid = blockIdx.x;               // 0..255
  const int ns  = bid & 127;                // n-strip; mt-partner on same XCD
  const int mt  = bid >> 7;
  const int n0  = ns * 32;
  const int m0  = mt * 128 + mh * 32;

  // ---- staging mapping: thread -> (tile kqs, n-row qn, oct j2 & j2+8)
  const int kqs = tid >> 8;                 // 0..3
  const int qn  = (tid & 255) >> 3;         // 0..31
  const int j2  = tid & 7;                  // octs j2 and j2+8 of row qn
  const unsigned wbase = (unsigned)(kqs * 16384);
  const unsigned wslot =
      ((unsigned)(qn * 256 + j2 * 16)) ^ ((unsigned)(qn & 7) << 4);

  // ---- preload all 8 steps' packed q (2 u16 per step, coalesced rows)
  const char* qpb = reinterpret_cast<const char*>(qp) +
      (size_t)(kqs * 32 + (j2 >> 2)) * 32768 + (size_t)(n0 + qn) * 8 +
      (j2 & 3) * 2;
#define QLDB(OFF) ((unsigned)*reinterpret_cast<const unsigned short*>(qpb + (OFF)))
  const unsigned QA0 = QLDB(0),       QB0 = QLDB(65536);
  const unsigned QA1 = QLDB(131072),  QB1 = QLDB(196608);
  const unsigned QA2 = QLDB(262144),  QB2 = QLDB(327680);
  const unsigned QA3 = QLDB(393216),  QB3 = QLDB(458752);
  const unsigned QA4 = QLDB(524288),  QB4 = QLDB(589824);
  const unsigned QA5 = QLDB(655360),  QB5 = QLDB(720896);
  const unsigned QA6 = QLDB(786432),  QB6 = QLDB(851968);
  const unsigned QA7 = QLDB(917504),  QB7 = QLDB(983040);
#undef QLDB

  // ---- compute-side bases
  const char* axb = reinterpret_cast<const char*>(xa) +
      (size_t)kq * 524288 + (size_t)(m0 + l15) * 64 + l4 * 16;
  const unsigned kqW  = (unsigned)(kq * 16384);
  const unsigned swzB = (unsigned)(l15 & 7) << 4;
  const unsigned rbB  = (unsigned)(l15 * 256 + l4 * 16);
  const unsigned rk0 = (rbB +   0) ^ swzB;
  const unsigned rk1 = (rbB +  64) ^ swzB;
  const unsigned rk2 = (rbB + 128) ^ swzB;
  const unsigned rk3 = (rbB + 192) ^ swzB;

  bf16x8 AE_0, AE_1, AE_2, AE_3, AE_4, AE_5, AE_6, AE_7;
  bf16x8 AO_0, AO_1, AO_2, AO_3, AO_4, AO_5, AO_6, AO_7;
  f32x4  c00 = {}, c01 = {}, c10 = {}, c11 = {};

  AL(AE, 0);                                // in flight before tbl build

  // ---- signed codebook table: tbl[i] = 4 packed bf16, tbl[i+128] = -tbl[i]
  if (tid < 256) {
    int r = tid & 127, sg = tid >> 7;
    unsigned long long v = 0;
#pragma unroll
    for (int j = 0; j < 4; ++j) {
      float f = (float)D4_I8[r * 4 + j] * 0.5f;
      unsigned int b = __float_as_uint(f) ^ (sg ? 0x80000000u : 0u);
      v |= (unsigned long long)(b >> 16) << (16 * j);
    }
    tbl[tid] = v;
  }
  BAR();                                    // tbl ready
  STG2(QA0, QB0, 0);                        // stage step 0 into buf 0
  BAR();                                    // buf 0 ready

  // ---- 8 k-steps (128k each), lgkmcnt-only barrier per step
  STEPA(0, QA1, QB1); STEPB(1, QA2, QB2);
  STEPA(2, QA3, QB3); STEPB(3, QA4, QB4);
  STEPA(4, QA5, QB5); STEPB(5, QA6, QB6);
  STEPA(6, QA7, QB7);
  {                                         // step 7 (no prefetch)
    const char* wp_ = wsm + kqW + 8192;
    BREADS()
    MFMA16(AO, b00,b01,b10,b11,b20,b21,b30,b31);
  }
  BAR();                                    // all W reads done -> planes alias

  // ---- kq-reduction through LDS planes (alias W region), store once
#define PWR(C, MI, NI) do { \
    pl[((MI) * 16 + l4 * 4 + 0) * 36 + (NI) * 16 + l15] = C[0]; \
    pl[((MI) * 16 + l4 * 4 + 1) * 36 + (NI) * 16 + l15] = C[1]; \
    pl[((MI) * 16 + l4 * 4 + 2) * 36 + (NI) * 16 + l15] = C[2]; \
    pl[((MI) * 16 + l4 * 4 + 3) * 36 + (NI) * 16 + l15] = C[3]; } while (0)
#define PRD(C, MI, NI) do { \
    C[0] += pl[((MI) * 16 + l4 * 4 + 0) * 36 + (NI) * 16 + l15]; \
    C[1] += pl[((MI) * 16 + l4 * 4 + 1) * 36 + (NI) * 16 + l15]; \
    C[2] += pl[((MI) * 16 + l4 * 4 + 2) * 36 + (NI) * 16 + l15]; \
    C[3] += pl[((MI) * 16 + l4 * 4 + 3) * 36 + (NI) * 16 + l15]; } while (0)

  if (kq) {
    float* pl = redp + (size_t)(mh * 3 + kq - 1) * 1152;   // 32x36 plane
    PWR(c00, 0, 0); PWR(c01, 0, 1); PWR(c10, 1, 0); PWR(c11, 1, 1);
  }
  __syncthreads();
  if (kq == 0) {
#pragma unroll
    for (int p = 0; p < 3; ++p) {
      const float* pl = redp + (size_t)(mh * 3 + p) * 1152;
      PRD(c00, 0, 0); PRD(c01, 0, 1); PRD(c10, 1, 0); PRD(c11, 1, 1);
    }
    float* ob = out + (size_t)(m0 + l4 * 4) * MOUT + n0 + l15;
#define STO(C, MI, NI) do { \
    ob[(size_t)((MI) * 16 + 0) * MOUT + (NI) * 16] = C[0]; \
    ob[(size_t)((MI) * 16 + 1) * MOUT + (NI) * 16] = C[1]; \
    ob[(size_t)((MI) * 16 + 2) * MOUT + (NI) * 16] = C[2]; \
    ob[(size_t)((MI) * 16 + 3) * MOUT + (NI) * 16] = C[3]; } while (0)
    STO(c00, 0, 0); STO(c01, 0, 1); STO(c10, 1, 0); STO(c11, 1, 1);
#undef STO
  }
#undef PWR
#undef PRD
}

extern "C" void kernel_launch(void* const* d_in, const int* in_sizes, int n_in,
                              void* d_out, int out_size, void* d_ws, size_t ws_size,
                              hipStream_t stream) {
  const float* inp = (const float*)d_in[0];
  const float* sw  = (const float*)d_in[1];
  const float* qs  = (const float*)d_in[2];
  const int*   qi  = (const int*)d_in[3];
  float* out = (float*)d_out;
  unsigned short* xa = (unsigned short*)d_ws;                       // 2 MB
  unsigned short* qp = (unsigned short*)((char*)d_ws + (4 << 20));  // 4 MB

  prep_kernel<<<640, 256, 0, stream>>>(inp, sw, qs, qi, xa, qp);
  gemm_kernel<<<256, 1024, 0, stream>>>(xa, qp, out);
}